// Round 1
// baseline (249.115 us; speedup 1.0000x reference)
//
#include <hip/hip_runtime.h>

// HATS hyperparameters (match reference)
#define KK 10
#define RR 3
#define TAU_F 1.0e6f
#define DELTA_T_F 1.0e5f
#define GW_ 24
#define NC_ 432
#define SS_ 7          // 2R+1

// One thread per (b, i) event. For each valid center event i, scan causal
// window backwards (t sorted -> break when dt > DELTA_T), accumulate
// exp(-dt/tau) into hist[b, cell_i, p_i, dy, dx] via atomics, and bump the
// per-(b,cell) valid-event count once.
__global__ void hats_pair_kernel(const float4* __restrict__ ev,
                                 const int* __restrict__ lengths,
                                 float* __restrict__ hist,
                                 float* __restrict__ counts,
                                 int B, int T) {
    int gid = blockIdx.x * blockDim.x + threadIdx.x;
    if (gid >= B * T) return;
    int b = gid / T;
    int i = gid - b * T;
    int len = lengths[b];
    if (i >= len) return;

    float4 ei = ev[gid];
    int xi = (int)ei.x;
    int yi = (int)ei.y;
    int pi = (int)ei.w;
    float ti = ei.z;
    int ci = (yi / KK) * GW_ + (xi / KK);

    // per-cell valid event count (once per valid event)
    atomicAdd(&counts[b * NC_ + ci], 1.0f);

    float* base = hist + (size_t)((b * NC_ + ci) * 2 + pi) * (SS_ * SS_);
    const float4* evb = ev + (size_t)b * T;

    for (int j = i; j >= 0; --j) {
        float4 ej = evb[j];
        float dt = ti - ej.z;           // >= 0 since t sorted ascending
        if (dt > DELTA_T_F) break;      // all earlier j have even larger dt
        int dx = (int)ej.x - xi + RR;   // x_j - x_i + R
        int dy = (int)ej.y - yi + RR;
        if ((unsigned)dx < SS_ && (unsigned)dy < SS_) {
            int cj = ((int)ej.y / KK) * GW_ + ((int)ej.x / KK);
            if (cj == ci && (int)ej.w == pi) {
                atomicAdd(&base[dy * SS_ + dx], __expf(-dt * (1.0f / TAU_F)));
            }
        }
    }
}

// out[idx] /= max(counts[b*NC + c], 1);  idx = ((b*NC + c)*2 + p)*49 + s
__global__ void hats_norm_kernel(float* __restrict__ out,
                                 const float* __restrict__ counts,
                                 int total) {
    int idx = blockIdx.x * blockDim.x + threadIdx.x;
    if (idx >= total) return;
    int bc = idx / (2 * SS_ * SS_);
    out[idx] *= __frcp_rn(fmaxf(counts[bc], 1.0f));
}

extern "C" void kernel_launch(void* const* d_in, const int* in_sizes, int n_in,
                              void* d_out, int out_size, void* d_ws, size_t ws_size,
                              hipStream_t stream) {
    const float* events = (const float*)d_in[0];  // [B, T, 4] f32
    const int* lengths  = (const int*)d_in[1];    // [B] i32
    float* out = (float*)d_out;                   // [B, NC, 2, 7, 7] f32
    float* counts = (float*)d_ws;                 // [B, NC] f32 scratch

    int B = in_sizes[1];                // 8
    int T = in_sizes[0] / (B * 4);      // 2048

    // Harness poisons d_out and d_ws with 0xAA before every timed call.
    hipMemsetAsync(d_out, 0, sizeof(float) * (size_t)out_size, stream);
    hipMemsetAsync(d_ws, 0, sizeof(float) * (size_t)(B * NC_), stream);

    int n = B * T;
    hats_pair_kernel<<<(n + 255) / 256, 256, 0, stream>>>(
        (const float4*)events, lengths, out, counts, B, T);

    hats_norm_kernel<<<(out_size + 255) / 256, 256, 0, stream>>>(
        out, counts, out_size);
}

// Round 2
// 73.055 us; speedup vs baseline: 3.4099x; 3.4099x over previous
//
#include <hip/hip_runtime.h>

// HATS hyperparameters (match reference)
#define KK 10
#define RR 3
#define TAU_F 1.0e6f
#define DELTA_T_F 1.0e5f
#define GW_ 24
#define NC_ 432
#define SS_ 7          // 2R+1

// Zero hist (d_out) and counts (d_ws) in one dispatch (harness poisons both).
__global__ void hats_zero_kernel(float* __restrict__ out, int n_out,
                                 float* __restrict__ counts, int n_counts) {
    int idx = blockIdx.x * blockDim.x + threadIdx.x;
    if (idx < n_out) out[idx] = 0.0f;
    if (idx < n_counts) counts[idx] = 0.0f;
}

// One WAVE per (b, i) event. Lane l probes j = i-l, i-l-64, ... ; since t is
// sorted ascending, dt = t_i - t_j grows as j decreases, so the wave breaks
// once no lane is still inside the DELTA_T window. Serial depth ~ (window/64).
__global__ void hats_pair_wave(const float4* __restrict__ ev,
                               const int* __restrict__ lengths,
                               float* __restrict__ hist,
                               float* __restrict__ counts,
                               int B, int T) {
    int gtid = blockIdx.x * blockDim.x + threadIdx.x;
    int w    = gtid >> 6;   // wave id == event id
    int lane = gtid & 63;
    if (w >= B * T) return;
    int b = w / T;
    int i = w - b * T;
    if (i >= lengths[b]) return;          // wave-uniform exit

    float4 ei = ev[w];                    // same addr all lanes -> broadcast
    int   xi = (int)ei.x;
    int   yi = (int)ei.y;
    int   pi = (int)ei.w;
    float ti = ei.z;
    int   ci = (yi / KK) * GW_ + (xi / KK);

    if (lane == 0) atomicAdd(&counts[b * NC_ + ci], 1.0f);

    float* base = hist + (size_t)((b * NC_ + ci) * 2 + pi) * (SS_ * SS_);
    const float4* evb = ev + (size_t)b * T;

    for (int j = i - lane; ; j -= 64) {
        float dt = 1.0e30f;               // lanes past j<0 count as out-of-window
        if (j >= 0) {
            float4 ej = evb[j];
            dt = ti - ej.z;               // >= 0 (t sorted, j <= i)
            if (dt <= DELTA_T_F) {
                int dx = (int)ej.x - xi + RR;
                int dy = (int)ej.y - yi + RR;
                if ((unsigned)dx < SS_ && (unsigned)dy < SS_) {
                    int cj = ((int)ej.y / KK) * GW_ + ((int)ej.x / KK);
                    if (cj == ci && (int)ej.w == pi) {
                        atomicAdd(&base[dy * SS_ + dx],
                                  __expf(-dt * (1.0f / TAU_F)));
                    }
                }
            }
        }
        // continue only if some lane can still find in-window work below
        if (!__any(j >= 64 && dt <= DELTA_T_F)) break;
    }
}

// out[idx] /= max(counts[idx / 98], 1)
__global__ void hats_norm_kernel(float* __restrict__ out,
                                 const float* __restrict__ counts,
                                 int total) {
    int idx = blockIdx.x * blockDim.x + threadIdx.x;
    if (idx >= total) return;
    int bc = idx / (2 * SS_ * SS_);
    out[idx] *= __frcp_rn(fmaxf(counts[bc], 1.0f));
}

extern "C" void kernel_launch(void* const* d_in, const int* in_sizes, int n_in,
                              void* d_out, int out_size, void* d_ws, size_t ws_size,
                              hipStream_t stream) {
    const float* events = (const float*)d_in[0];  // [B, T, 4] f32
    const int* lengths  = (const int*)d_in[1];    // [B] i32
    float* out = (float*)d_out;                   // [B, NC, 2, 7, 7] f32
    float* counts = (float*)d_ws;                 // [B, NC] f32 scratch

    int B = in_sizes[1];                // 8
    int T = in_sizes[0] / (B * 4);      // 2048
    int n_counts = B * NC_;

    hats_zero_kernel<<<(out_size + 255) / 256, 256, 0, stream>>>(
        out, out_size, counts, n_counts);

    int n_threads = B * T * 64;         // one wave per event
    hats_pair_wave<<<(n_threads + 255) / 256, 256, 0, stream>>>(
        (const float4*)events, lengths, out, counts, B, T);

    hats_norm_kernel<<<(out_size + 255) / 256, 256, 0, stream>>>(
        out, counts, out_size);
}

// Round 3
// 61.276 us; speedup vs baseline: 4.0654x; 1.1922x over previous
//
#include <hip/hip_runtime.h>

// HATS hyperparameters (match reference)
#define KK 10
#define RR 3
#define TAU_F 1.0e6f
#define DELTA_T_F 1.0e5f
#define GW_ 24
#define NC_ 432
#define SS_ 7              // 2R+1
#define NBIN 98            // 2 * 7 * 7
#define MAXEV 2048

// One workgroup per (b, cell). Gather-style: build the cell's event list in
// LDS, do the tiny n^2 causal-pair accumulation in LDS, write 98 outputs once.
// No global atomics, no zero pass, no workspace.
__global__ __launch_bounds__(256) void hats_cell_kernel(
        const float4* __restrict__ ev,      // [B, T] (x,y,t,p)
        const int* __restrict__ lengths,    // [B]
        float* __restrict__ out,            // [B, NC, 2, 7, 7]
        int T) {
    __shared__ int   s_idx[MAXEV];          // original event indices in this cell
    __shared__ float s_hist[NBIN];
    __shared__ int   s_n;

    int blk  = blockIdx.x;
    int b    = blk / NC_;
    int cell = blk - b * NC_;
    int tid  = threadIdx.x;

    if (tid == 0) s_n = 0;
    if (tid < NBIN) s_hist[tid] = 0.0f;
    __syncthreads();

    int len = lengths[b];
    const float4* evb = ev + (size_t)b * T;

    // Phase 1: compact indices of valid events belonging to this cell.
    for (int j = tid; j < len; j += 256) {
        float4 e = evb[j];
        int cj = ((int)e.y / KK) * GW_ + ((int)e.x / KK);
        if (cj == cell) {
            int slot = atomicAdd(&s_n, 1);
            s_idx[slot] = j;
        }
    }
    __syncthreads();

    int n = s_n;

    // Phase 2: causal pairs within the cell. Pair space n*n (tiny, ~13 avg).
    for (int pidx = tid; pidx < n * n; pidx += 256) {
        int ai = pidx / n;                  // center candidate
        int aj = pidx - ai * n;             // contributor candidate
        int ii = s_idx[ai];
        int jj = s_idx[aj];
        if (jj > ii) continue;              // causality: j <= i
        float4 e_i = evb[ii];
        float4 e_j = evb[jj];
        if ((int)e_j.w != (int)e_i.w) continue;   // same polarity
        float dt = e_i.z - e_j.z;                 // >= 0 (t sorted)
        if (dt > DELTA_T_F) continue;
        int dx = (int)e_j.x - (int)e_i.x + RR;
        int dy = (int)e_j.y - (int)e_i.y + RR;
        if ((unsigned)dx >= SS_ || (unsigned)dy >= SS_) continue;
        int p = (int)e_i.w;
        atomicAdd(&s_hist[(p * SS_ + dy) * SS_ + dx],
                  __expf(-dt * (1.0f / TAU_F)));
    }
    __syncthreads();

    // Phase 3: normalize by valid-event count in cell, write 98 outputs.
    float inv = __frcp_rn(fmaxf((float)n, 1.0f));
    float* obase = out + (size_t)blk * NBIN;
    if (tid < NBIN) obase[tid] = s_hist[tid] * inv;
}

extern "C" void kernel_launch(void* const* d_in, const int* in_sizes, int n_in,
                              void* d_out, int out_size, void* d_ws, size_t ws_size,
                              hipStream_t stream) {
    const float* events = (const float*)d_in[0];  // [B, T, 4] f32
    const int* lengths  = (const int*)d_in[1];    // [B] i32
    float* out = (float*)d_out;                   // [B, NC, 2, 7, 7] f32

    int B = in_sizes[1];                // 8
    int T = in_sizes[0] / (B * 4);      // 2048

    hats_cell_kernel<<<B * NC_, 256, 0, stream>>>(
        (const float4*)events, lengths, out, T);
}

// Round 4
// 59.209 us; speedup vs baseline: 4.2074x; 1.0349x over previous
//
#include <hip/hip_runtime.h>

// HATS hyperparameters (match reference)
#define KK 10
#define RR 3
#define TAU_F 1.0e6f
#define DELTA_T_F 1.0e5f
#define GW_ 24
#define NC_ 432
#define SS_ 7              // 2R+1
#define NBIN 98            // 2 * 7 * 7
#define G_ 6               // cells per block
#define NGRP (NC_ / G_)    // 72 groups
#define MAXEV 2048

// One workgroup per (b, cell-group of 6 consecutive cell ids).
// Phase 1: prefetch-unrolled scan of the batch's events; compact this group's
//          events into LDS as (t, key) where key packs x,y,p,local-cell,idx.
// Phase 2: single pass over the m*m pair space of the whole group (causality
//          and cell-match via key bits), accumulate exp(-dt/tau) in LDS hist.
// Phase 3: normalize per cell, write 6*98 contiguous outputs once.
__global__ __launch_bounds__(256) void hats_group_kernel(
        const float4* __restrict__ ev,      // [B, T] (x,y,t,p)
        const int* __restrict__ lengths,    // [B]
        float* __restrict__ out,            // [B, NC, 2, 7, 7]
        int T) {
    __shared__ float s_t[MAXEV];
    __shared__ int   s_key[MAXEV];          // x | y<<8 | p<<16 | local<<17 | idx<<20
    __shared__ float s_hist[G_ * NBIN];
    __shared__ float s_inv[G_];
    __shared__ int   s_cnt[G_];
    __shared__ int   s_m;

    int blk = blockIdx.x;
    int b   = blk / NGRP;
    int g   = blk - b * NGRP;               // group id: cells [6g, 6g+6)
    int c0  = g * G_;
    int tid = threadIdx.x;

    if (tid == 0) s_m = 0;
    if (tid < G_) s_cnt[tid] = 0;
    for (int o = tid; o < G_ * NBIN; o += 256) s_hist[o] = 0.0f;
    __syncthreads();

    int len = lengths[b];
    const float4* evb = ev + (size_t)b * T;

    // ---- Phase 1: prefetch 8 events/thread, then filter+compact ----
    float4 e[8];
#pragma unroll
    for (int k = 0; k < 8; ++k) {
        int j = tid + (k << 8);
        int ja = j < len ? j : (len - 1);   // clamped safe address
        e[k] = evb[ja];
    }
#pragma unroll
    for (int k = 0; k < 8; ++k) {
        int j = tid + (k << 8);
        if (j < len) {
            int xi = (int)e[k].x;
            int yi = (int)e[k].y;
            int cell = (yi / KK) * GW_ + (xi / KK);
            int local = cell - c0;
            if ((unsigned)local < G_) {
                int slot = atomicAdd(&s_m, 1);
                s_t[slot] = e[k].z;
                s_key[slot] = xi | (yi << 8) | ((int)e[k].w << 16)
                            | (local << 17) | (j << 20);
                atomicAdd(&s_cnt[local], 1);
            }
        }
    }
    __syncthreads();

    int m = s_m;

    // ---- Phase 2: all m*m ordered pairs of the group ----
    for (int pidx = tid; pidx < m * m; pidx += 256) {
        int ia = pidx / m;                  // center candidate i
        int ib = pidx - ia * m;             // contributor candidate j
        int ka = s_key[ia];
        int kb = s_key[ib];
        // causality: original idx_j <= idx_i (bits 20..30, same sign region)
        if ((kb >> 20) > (ka >> 20)) continue;
        // same local cell and polarity: bits 16..19 equal
        if (((ka ^ kb) & 0x000F0000) != 0) continue;
        float dt = s_t[ia] - s_t[ib];       // >= 0 (t sorted by idx)
        if (dt > DELTA_T_F) continue;
        int dx = (kb & 0xFF) - (ka & 0xFF) + RR;
        int dy = ((kb >> 8) & 0xFF) - ((ka >> 8) & 0xFF) + RR;
        if ((unsigned)dx >= SS_ || (unsigned)dy >= SS_) continue;
        int local = (ka >> 17) & 7;
        int p     = (ka >> 16) & 1;
        atomicAdd(&s_hist[local * NBIN + (p * SS_ + dy) * SS_ + dx],
                  __expf(-dt * (1.0f / TAU_F)));
    }
    __syncthreads();

    if (tid < G_) s_inv[tid] = __frcp_rn(fmaxf((float)s_cnt[tid], 1.0f));
    __syncthreads();

    // ---- Phase 3: write 6*98 contiguous outputs ----
    float* obase = out + ((size_t)(b * NC_ + c0)) * NBIN;
    for (int o = tid; o < G_ * NBIN; o += 256) {
        int c = o / NBIN;
        obase[o] = s_hist[o] * s_inv[c];
    }
}

extern "C" void kernel_launch(void* const* d_in, const int* in_sizes, int n_in,
                              void* d_out, int out_size, void* d_ws, size_t ws_size,
                              hipStream_t stream) {
    const float* events = (const float*)d_in[0];  // [B, T, 4] f32
    const int* lengths  = (const int*)d_in[1];    // [B] i32
    float* out = (float*)d_out;                   // [B, NC, 2, 7, 7] f32

    int B = in_sizes[1];                // 8
    int T = in_sizes[0] / (B * 4);      // 2048

    hats_group_kernel<<<B * NGRP, 256, 0, stream>>>(
        (const float4*)events, lengths, out, T);
}